// Round 1
// baseline (274.983 us; speedup 1.0000x reference)
//
#include <hip/hip_runtime.h>

#define D_IN  128
#define D_OUT 32
#define H     512
#define W     512
#define W4    128   // W / 4 (float4 lanes per row)

__device__ __forceinline__ float gw(int k, float inv2) {
    float d = (float)(k - 4);
    return expf(-d * d * inv2);
}

// Pass 1: depth conv, stride 4, pad 3.  inp (128,512,512) -> out (32,512,512)
__global__ void zconv_kernel(const float* __restrict__ inp, float* __restrict__ out,
                             const float* __restrict__ bet_z_p) {
    int tid = blockIdx.x * blockDim.x + threadIdx.x;
    int w4 = tid & (W4 - 1);
    int h  = (tid >> 7) & (H - 1);
    int d  = tid >> 16;
    float bz   = bet_z_p[0];
    float inv2 = 1.0f / (2.0f * bz * bz);
    const float4* in4 = (const float4*)inp;
    float4 acc = make_float4(0.f, 0.f, 0.f, 0.f);
    int base = h * W4 + w4;
#pragma unroll
    for (int k = 0; k < 9; ++k) {
        int din = 4 * d - 3 + k;
        if (din < 0 || din >= D_IN) continue;
        float wt = gw(k, inv2);
        float4 v = in4[din * (H * W4) + base];
        acc.x += v.x * wt; acc.y += v.y * wt; acc.z += v.z * wt; acc.w += v.w * wt;
    }
    ((float4*)out)[d * (H * W4) + base] = acc;
}

// Pass 2: conv along H (x axis), pad 4.
__global__ void hconv_kernel(const float* __restrict__ in, float* __restrict__ out,
                             const float* __restrict__ bet_xy_p) {
    int tid = blockIdx.x * blockDim.x + threadIdx.x;
    int w4 = tid & (W4 - 1);
    int h  = (tid >> 7) & (H - 1);
    int d  = tid >> 16;
    float b    = bet_xy_p[0];
    float inv2 = 1.0f / (2.0f * b * b);
    const float4* in4 = (const float4*)in;
    float4 acc = make_float4(0.f, 0.f, 0.f, 0.f);
#pragma unroll
    for (int k = 0; k < 9; ++k) {
        int hh = h - 4 + k;
        if (hh < 0 || hh >= H) continue;
        float wt = gw(k, inv2);
        float4 v = in4[(d * H + hh) * W4 + w4];
        acc.x += v.x * wt; acc.y += v.y * wt; acc.z += v.z * wt; acc.w += v.w * wt;
    }
    ((float4*)out)[(d * H + h) * W4 + w4] = acc;
}

// Pass 3: conv along W (y axis), pad 4, fused per-block min/max.
__global__ void wconv_kernel(const float* __restrict__ in, float* __restrict__ out,
                             const float* __restrict__ bet_xy_p,
                             float* __restrict__ blkMin, float* __restrict__ blkMax) {
    int tid = blockIdx.x * blockDim.x + threadIdx.x;
    int w4 = tid & (W4 - 1);
    int h  = (tid >> 7) & (H - 1);
    int d  = tid >> 16;
    float b    = bet_xy_p[0];
    float inv2 = 1.0f / (2.0f * b * b);
    float wt[9];
#pragma unroll
    for (int k = 0; k < 9; ++k) wt[k] = gw(k, inv2);

    const float4* in4 = (const float4*)in;
    int row = (d * H + h) * W4;
    float4 z4 = make_float4(0.f, 0.f, 0.f, 0.f);
    float4 va = (w4 > 0)      ? in4[row + w4 - 1] : z4;
    float4 vb =                 in4[row + w4];
    float4 vc = (w4 < W4 - 1) ? in4[row + w4 + 1] : z4;
    float win[12] = {va.x, va.y, va.z, va.w,
                     vb.x, vb.y, vb.z, vb.w,
                     vc.x, vc.y, vc.z, vc.w};
    float4 o = make_float4(0.f, 0.f, 0.f, 0.f);
#pragma unroll
    for (int k = 0; k < 9; ++k) {
        o.x += win[k]     * wt[k];
        o.y += win[k + 1] * wt[k];
        o.z += win[k + 2] * wt[k];
        o.w += win[k + 3] * wt[k];
    }
    ((float4*)out)[row + w4] = o;

    // block min/max reduction
    float lmin = fminf(fminf(o.x, o.y), fminf(o.z, o.w));
    float lmax = fmaxf(fmaxf(o.x, o.y), fmaxf(o.z, o.w));
#pragma unroll
    for (int off = 32; off > 0; off >>= 1) {
        lmin = fminf(lmin, __shfl_down(lmin, off, 64));
        lmax = fmaxf(lmax, __shfl_down(lmax, off, 64));
    }
    __shared__ float smin[4], smax[4];
    int lane = threadIdx.x & 63, wv = threadIdx.x >> 6;
    if (lane == 0) { smin[wv] = lmin; smax[wv] = lmax; }
    __syncthreads();
    if (threadIdx.x == 0) {
        blkMin[blockIdx.x] = fminf(fminf(smin[0], smin[1]), fminf(smin[2], smin[3]));
        blkMax[blockIdx.x] = fmaxf(fmaxf(smax[0], smax[1]), fmaxf(smax[2], smax[3]));
    }
}

// Pass 4: reduce per-block min/max (8192 entries) with one block.
__global__ void reduce_kernel(const float* __restrict__ blkMin, const float* __restrict__ blkMax,
                              float* __restrict__ fin, int nblk) {
    float lmin =  3.402823466e38f;
    float lmax = -3.402823466e38f;
    for (int i = threadIdx.x; i < nblk; i += blockDim.x) {
        lmin = fminf(lmin, blkMin[i]);
        lmax = fmaxf(lmax, blkMax[i]);
    }
#pragma unroll
    for (int off = 32; off > 0; off >>= 1) {
        lmin = fminf(lmin, __shfl_down(lmin, off, 64));
        lmax = fmaxf(lmax, __shfl_down(lmax, off, 64));
    }
    __shared__ float smin[4], smax[4];
    int lane = threadIdx.x & 63, wv = threadIdx.x >> 6;
    if (lane == 0) { smin[wv] = lmin; smax[wv] = lmax; }
    __syncthreads();
    if (threadIdx.x == 0) {
        fin[0] = fminf(fminf(smin[0], smin[1]), fminf(smin[2], smin[3]));
        fin[1] = fmaxf(fmaxf(smax[0], smax[1]), fmaxf(smax[2], smax[3]));
    }
}

// Pass 5: normalize.
__global__ void norm_kernel(const float* __restrict__ in, float* __restrict__ out,
                            const float* __restrict__ fin) {
    int tid = blockIdx.x * blockDim.x + threadIdx.x;
    float mn  = fin[0];
    float inv = 1.0f / (fin[1] - mn);
    float4 v = ((const float4*)in)[tid];
    float4 o = make_float4((v.x - mn) * inv, (v.y - mn) * inv,
                           (v.z - mn) * inv, (v.w - mn) * inv);
    ((float4*)out)[tid] = o;
}

extern "C" void kernel_launch(void* const* d_in, const int* in_sizes, int n_in,
                              void* d_out, int out_size, void* d_ws, size_t ws_size,
                              hipStream_t stream) {
    const float* inp    = (const float*)d_in[0];
    // d_in[1]=mu_z, d_in[2]=sig_z: only produce a positive global scale,
    // which cancels exactly in the min-max normalization -> unused.
    const float* bet_xy = (const float*)d_in[3];
    const float* bet_z  = (const float*)d_in[4];
    float* out = (float*)d_out;

    char* ws = (char*)d_ws;
    float* fin    = (float*)ws;                  // 2 floats (final min/max)
    float* blkMin = (float*)(ws + 256);          // 8192 floats
    float* blkMax = (float*)(ws + 256 + 32768);  // 8192 floats
    float* bufA   = (float*)(ws + 256 + 65536);  // 32 MiB ping-pong buffer

    const int NTH  = D_OUT * H * W4;  // 2,097,152 float4 threads
    const int BLK  = 256;
    const int GRID = NTH / BLK;       // 8192

    // inp -> A (z-conv, 4x depth reduction first = least work downstream)
    zconv_kernel<<<GRID, BLK, 0, stream>>>(inp, bufA, bet_z);
    // A -> d_out (h-conv)
    hconv_kernel<<<GRID, BLK, 0, stream>>>(bufA, out, bet_xy);
    // d_out -> A (w-conv + per-block min/max)
    wconv_kernel<<<GRID, BLK, 0, stream>>>(out, bufA, bet_xy, blkMin, blkMax);
    // final min/max
    reduce_kernel<<<1, BLK, 0, stream>>>(blkMin, blkMax, fin, GRID);
    // A -> d_out (normalize)
    norm_kernel<<<GRID, BLK, 0, stream>>>(bufA, out, fin);
}

// Round 2
// 242.267 us; speedup vs baseline: 1.1350x; 1.1350x over previous
//
#include <hip/hip_runtime.h>

#define D_IN  128
#define D_OUT 32
#define H     512
#define W     512
#define W4    128          // W/4 float4 lanes per row
#define HB    16           // output H rows per block
#define ZR    (HB + 8)     // z-conv rows incl. h-halo (24)
#define NTHR  512

// Fused separable 3D conv: z (stride4,pad3) -> h (pad4) -> w (pad4), one block
// per (d, 16-row H tile). LDS: zbuf 48K + hbuf 32K = 80K -> 2 blocks/CU.
__global__ __launch_bounds__(NTHR)
void conv3d_fused(const float* __restrict__ inp, float* __restrict__ out,
                  const float* __restrict__ bxy_p, const float* __restrict__ bz_p,
                  float* __restrict__ blkMin, float* __restrict__ blkMax) {
    __shared__ float zbuf[ZR * W];   // 48 KiB
    __shared__ float hbuf[HB * W];   // 32 KiB

    const int d  = blockIdx.x >> 5;        // 32 h-tiles per output slice
    const int h0 = (blockIdx.x & 31) * HB;

    const float bz = bz_p[0], bx = bxy_p[0];
    const float iz = 1.0f / (2.0f * bz * bz);
    const float ix = 1.0f / (2.0f * bx * bx);
    float wz[9], wx[9];
#pragma unroll
    for (int k = 0; k < 9; ++k) {
        float dd = (float)(k - 4);
        wz[k] = expf(-dd * dd * iz);
        wx[k] = expf(-dd * dd * ix);
    }

    const float4* in4 = (const float4*)inp;
    float4* z4 = (float4*)zbuf;
    float4* h4 = (float4*)hbuf;

    // ---- Step 1: z-conv (stride 4, pad 3) into zbuf rows [h0-4, h0+20) ----
    for (int t = threadIdx.x; t < ZR * W4; t += NTHR) {
        int r  = t >> 7;            // 0..23
        int c4 = t & (W4 - 1);
        int h  = h0 - 4 + r;
        float4 acc = make_float4(0.f, 0.f, 0.f, 0.f);
        if ((unsigned)h < H) {
            int base = h * W4 + c4;
#pragma unroll
            for (int k = 0; k < 9; ++k) {
                int din = 4 * d - 3 + k;
                if ((unsigned)din < D_IN) {
                    float4 v = in4[din * (H * W4) + base];
                    acc.x += v.x * wz[k]; acc.y += v.y * wz[k];
                    acc.z += v.z * wz[k]; acc.w += v.w * wz[k];
                }
            }
        }
        z4[t] = acc;
    }
    __syncthreads();

    // ---- Step 2: h-conv (pad 4) zbuf -> hbuf ----
    for (int t = threadIdx.x; t < HB * W4; t += NTHR) {
        int r  = t >> 7;
        int c4 = t & (W4 - 1);
        float4 acc = make_float4(0.f, 0.f, 0.f, 0.f);
#pragma unroll
        for (int k = 0; k < 9; ++k) {
            float4 v = z4[(r + k) * W4 + c4];
            acc.x += v.x * wx[k]; acc.y += v.y * wx[k];
            acc.z += v.z * wx[k]; acc.w += v.w * wx[k];
        }
        h4[t] = acc;
    }
    __syncthreads();

    // ---- Step 3: w-conv (pad 4) hbuf -> global, fused block min/max ----
    float lmin =  3.402823466e38f;
    float lmax = -3.402823466e38f;
    float4* out4 = (float4*)out;
    for (int t = threadIdx.x; t < HB * W4; t += NTHR) {
        int r  = t >> 7;
        int c4 = t & (W4 - 1);
        float4 zv = make_float4(0.f, 0.f, 0.f, 0.f);
        float4 va = (c4 > 0)      ? h4[r * W4 + c4 - 1] : zv;
        float4 vb =                 h4[r * W4 + c4];
        float4 vc = (c4 < W4 - 1) ? h4[r * W4 + c4 + 1] : zv;
        float win[12] = {va.x, va.y, va.z, va.w,
                         vb.x, vb.y, vb.z, vb.w,
                         vc.x, vc.y, vc.z, vc.w};
        float4 o = make_float4(0.f, 0.f, 0.f, 0.f);
#pragma unroll
        for (int k = 0; k < 9; ++k) {
            o.x += win[k]     * wx[k];
            o.y += win[k + 1] * wx[k];
            o.z += win[k + 2] * wx[k];
            o.w += win[k + 3] * wx[k];
        }
        out4[(d * H + h0 + r) * W4 + c4] = o;
        lmin = fminf(lmin, fminf(fminf(o.x, o.y), fminf(o.z, o.w)));
        lmax = fmaxf(lmax, fmaxf(fmaxf(o.x, o.y), fmaxf(o.z, o.w)));
    }

    // block reduction (8 waves); scratch aliases zbuf (not read in step 3)
#pragma unroll
    for (int off = 32; off > 0; off >>= 1) {
        lmin = fminf(lmin, __shfl_down(lmin, off, 64));
        lmax = fmaxf(lmax, __shfl_down(lmax, off, 64));
    }
    float* smin = &zbuf[0];
    float* smax = &zbuf[16];
    int lane = threadIdx.x & 63, wv = threadIdx.x >> 6;  // wv 0..7
    if (lane == 0) { smin[wv] = lmin; smax[wv] = lmax; }
    __syncthreads();
    if (threadIdx.x == 0) {
        float mn = smin[0], mx = smax[0];
#pragma unroll
        for (int i = 1; i < 8; ++i) { mn = fminf(mn, smin[i]); mx = fmaxf(mx, smax[i]); }
        blkMin[blockIdx.x] = mn;
        blkMax[blockIdx.x] = mx;
    }
}

// Reduce per-block min/max (1024 entries) with one block.
__global__ void reduce_kernel(const float* __restrict__ blkMin, const float* __restrict__ blkMax,
                              float* __restrict__ fin, int nblk) {
    float lmin =  3.402823466e38f;
    float lmax = -3.402823466e38f;
    for (int i = threadIdx.x; i < nblk; i += blockDim.x) {
        lmin = fminf(lmin, blkMin[i]);
        lmax = fmaxf(lmax, blkMax[i]);
    }
#pragma unroll
    for (int off = 32; off > 0; off >>= 1) {
        lmin = fminf(lmin, __shfl_down(lmin, off, 64));
        lmax = fmaxf(lmax, __shfl_down(lmax, off, 64));
    }
    __shared__ float smin[4], smax[4];
    int lane = threadIdx.x & 63, wv = threadIdx.x >> 6;
    if (lane == 0) { smin[wv] = lmin; smax[wv] = lmax; }
    __syncthreads();
    if (threadIdx.x == 0) {
        fin[0] = fminf(fminf(smin[0], smin[1]), fminf(smin[2], smin[3]));
        fin[1] = fmaxf(fmaxf(smax[0], smax[1]), fmaxf(smax[2], smax[3]));
    }
}

// Normalize.
__global__ void norm_kernel(const float* __restrict__ in, float* __restrict__ out,
                            const float* __restrict__ fin) {
    int tid = blockIdx.x * blockDim.x + threadIdx.x;
    float mn  = fin[0];
    float inv = 1.0f / (fin[1] - mn);
    float4 v = ((const float4*)in)[tid];
    ((float4*)out)[tid] = make_float4((v.x - mn) * inv, (v.y - mn) * inv,
                                      (v.z - mn) * inv, (v.w - mn) * inv);
}

extern "C" void kernel_launch(void* const* d_in, const int* in_sizes, int n_in,
                              void* d_out, int out_size, void* d_ws, size_t ws_size,
                              hipStream_t stream) {
    const float* inp    = (const float*)d_in[0];
    // mu_z / sig_z only produce a positive global scale, which cancels in the
    // min-max normalization -> unused.
    const float* bet_xy = (const float*)d_in[3];
    const float* bet_z  = (const float*)d_in[4];
    float* out = (float*)d_out;

    char* ws = (char*)d_ws;
    float* fin    = (float*)ws;                  // 2 floats
    float* blkMin = (float*)(ws + 4096);         // 1024 floats
    float* blkMax = (float*)(ws + 8192);         // 1024 floats
    float* bufA   = (float*)(ws + 65536);        // 32 MiB conv output

    const int CONV_GRID = D_OUT * (H / HB);      // 32 * 32 = 1024 blocks
    conv3d_fused<<<CONV_GRID, NTHR, 0, stream>>>(inp, bufA, bet_xy, bet_z, blkMin, blkMax);
    reduce_kernel<<<1, 256, 0, stream>>>(blkMin, blkMax, fin, CONV_GRID);

    const int NTASK = D_OUT * H * W4;            // 2,097,152 float4
    norm_kernel<<<NTASK / 256, 256, 0, stream>>>(bufA, out, fin);
}